// Round 1
// baseline (476.165 us; speedup 1.0000x reference)
//
#include <hip/hip_runtime.h>

// Problem constants (match reference)
#define C_CLASSES 10000
#define K_PROTO   4
#define D_DIM     2048
#define ROWS      (C_CLASSES * K_PROTO)   // 40000
#define D_VEC     (D_DIM / 4)             // 512 float4 per row

// Kernel 1: one wave (64 lanes) per prototype row. Each lane reads 8 float4
// (coalesced: lane i reads element j*64+i), accumulates squared diff vs the
// feature vector (8 KB, L1-resident), wave-shuffle reduces, lane 0 writes d[row].
__global__ __launch_bounds__(256) void dist_kernel(const float4* __restrict__ proto,
                                                   const float4* __restrict__ feat,
                                                   float* __restrict__ d_row) {
    const int wave = threadIdx.x >> 6;
    const int lane = threadIdx.x & 63;
    const int row  = blockIdx.x * 4 + wave;   // grid = ROWS/4 blocks of 4 waves
    const float4* p = proto + (size_t)row * D_VEC;

    float acc = 0.0f;
#pragma unroll
    for (int j = 0; j < 8; ++j) {
        const int idx = j * 64 + lane;
        const float4 pv = p[idx];
        const float4 fv = feat[idx];
        const float dx = pv.x - fv.x;
        const float dy = pv.y - fv.y;
        const float dz = pv.z - fv.z;
        const float dw = pv.w - fv.w;
        acc += dx * dx + dy * dy + dz * dz + dw * dw;
    }
    // wave64 reduction
#pragma unroll
    for (int off = 32; off > 0; off >>= 1)
        acc += __shfl_down(acc, off, 64);
    if (lane == 0) d_row[row] = acc;
}

// Kernel 2: single block. Stable logsumexp over 40000 values (160 KB, L2-hot)
// + label-row epilogue.
__global__ __launch_bounds__(256) void finalize_kernel(const float* __restrict__ d_row,
                                                       const int* __restrict__ label,
                                                       float* __restrict__ out) {
    __shared__ float red[256];
    const int tid = threadIdx.x;

    // Phase 1: min over d  (max logit = -min d)
    float lmin = 3.402823466e38f;
    for (int i = tid; i < ROWS; i += 256)
        lmin = fminf(lmin, d_row[i]);
    red[tid] = lmin;
    __syncthreads();
    for (int s = 128; s > 0; s >>= 1) {
        if (tid < s) red[tid] = fminf(red[tid], red[tid + s]);
        __syncthreads();
    }
    const float dmin = red[0];
    __syncthreads();

    // Phase 2: sum exp(dmin - d)
    float lsum = 0.0f;
    for (int i = tid; i < ROWS; i += 256)
        lsum += expf(dmin - d_row[i]);
    red[tid] = lsum;
    __syncthreads();
    for (int s = 128; s > 0; s >>= 1) {
        if (tid < s) red[tid] += red[tid + s];
        __syncthreads();
    }

    if (tid == 0) {
        // log_one = logsumexp(-d) = -dmin + log(sum exp(dmin - d))
        const float log_one = -dmin + logf(red[0]);
        const int lbl = label[0];
        float p = 0.0f;
#pragma unroll
        for (int k = 0; k < K_PROTO; ++k)
            p += log_one + d_row[lbl * K_PROTO + k];
        out[0] = p;
    }
}

extern "C" void kernel_launch(void* const* d_in, const int* in_sizes, int n_in,
                              void* d_out, int out_size, void* d_ws, size_t ws_size,
                              hipStream_t stream) {
    const float* feat  = (const float*)d_in[0];   // [2048] f32
    const int*   label = (const int*)d_in[1];     // [1] int32
    const float* proto = (const float*)d_in[2];   // [10000,4,2048] f32
    float* out   = (float*)d_out;                 // [1] f32
    float* d_row = (float*)d_ws;                  // 40000 f32 scratch (160 KB)

    dist_kernel<<<ROWS / 4, 256, 0, stream>>>(
        (const float4*)proto, (const float4*)feat, d_row);
    finalize_kernel<<<1, 256, 0, stream>>>(d_row, label, out);
}

// Round 2
// 459.991 us; speedup vs baseline: 1.0352x; 1.0352x over previous
//
#include <hip/hip_runtime.h>

// Problem constants (match reference)
#define C_CLASSES 10000
#define K_PROTO   4
#define D_DIM     2048
#define ROWS      (C_CLASSES * K_PROTO)   // 40000
#define D_VEC     (D_DIM / 4)             // 512 float4 per row
#define RPW       5                       // rows per wave
#define NBLOCKS   2000                    // 4 waves/block -> 8000 waves * 5 rows = 40000
#define NWAVES    (NBLOCKS * 4)

// Kernel 1: each wave handles 5 consecutive prototype rows (40 KB contiguous).
// Feature (8 KB) is loaded into registers once per wave and reused.
// Emits a per-wave exact local logsumexp pair: min_w, S_w = sum exp(min_w - d),
// plus the 4 label-row distances. No full d_row materialization.
__global__ __launch_bounds__(256) void dist_kernel(const float4* __restrict__ proto,
                                                   const float4* __restrict__ feat,
                                                   const int* __restrict__ label,
                                                   float* __restrict__ wave_min,
                                                   float* __restrict__ wave_sum,
                                                   float* __restrict__ d_label) {
    const int wave = (blockIdx.x << 2) | (threadIdx.x >> 6);
    const int lane = threadIdx.x & 63;
    const int row0 = wave * RPW;
    const int lbl  = label[0];

    // Feature into registers once (32 VGPRs)
    float4 f[8];
#pragma unroll
    for (int j = 0; j < 8; ++j) f[j] = feat[j * 64 + lane];

    float d[RPW];
#pragma unroll
    for (int r = 0; r < RPW; ++r) {
        const float4* p = proto + (size_t)(row0 + r) * D_VEC;
        float acc = 0.0f;
#pragma unroll
        for (int j = 0; j < 8; ++j) {
            const float4 pv = p[j * 64 + lane];
            const float dx = pv.x - f[j].x;
            const float dy = pv.y - f[j].y;
            const float dz = pv.z - f[j].z;
            const float dw = pv.w - f[j].w;
            acc += dx * dx + dy * dy + dz * dz + dw * dw;
        }
        // butterfly reduce: all 64 lanes end with the row sum
#pragma unroll
        for (int mask = 1; mask < 64; mask <<= 1)
            acc += __shfl_xor(acc, mask, 64);
        d[r] = acc;
    }

    // per-wave local logsumexp summary (redundant across lanes; lane 0 writes)
    float mw = d[0];
#pragma unroll
    for (int r = 1; r < RPW; ++r) mw = fminf(mw, d[r]);
    float sw = 0.0f;
#pragma unroll
    for (int r = 0; r < RPW; ++r) sw += expf(mw - d[r]);

    if (lane == 0) {
        wave_min[wave] = mw;
        wave_sum[wave] = sw;
#pragma unroll
        for (int r = 0; r < RPW; ++r) {
            const int row = row0 + r;
            if ((row >> 2) == lbl) d_label[row & 3] = d[r];
        }
    }
}

// Kernel 2: single block combines 8000 wave-local pairs (64 KB, L2/L3-hot):
// dmin = min_w;  one = sum_w S_w * exp(dmin - min_w);  then epilogue.
__global__ __launch_bounds__(256) void finalize_kernel(const float* __restrict__ wave_min,
                                                       const float* __restrict__ wave_sum,
                                                       const float* __restrict__ d_label,
                                                       float* __restrict__ out) {
    __shared__ float red[256];
    const int tid = threadIdx.x;

    float m = 3.402823466e38f;
    for (int i = tid; i < NWAVES; i += 256) m = fminf(m, wave_min[i]);
    red[tid] = m;
    __syncthreads();
    for (int s = 128; s > 0; s >>= 1) {
        if (tid < s) red[tid] = fminf(red[tid], red[tid + s]);
        __syncthreads();
    }
    const float dmin = red[0];
    __syncthreads();

    float acc = 0.0f;
    for (int i = tid; i < NWAVES; i += 256)
        acc += wave_sum[i] * expf(dmin - wave_min[i]);
    red[tid] = acc;
    __syncthreads();
    for (int s = 128; s > 0; s >>= 1) {
        if (tid < s) red[tid] += red[tid + s];
        __syncthreads();
    }

    if (tid == 0) {
        const float log_one = -dmin + logf(red[0]);
        float p = 0.0f;
#pragma unroll
        for (int k = 0; k < K_PROTO; ++k) p += log_one + d_label[k];
        out[0] = p;
    }
}

extern "C" void kernel_launch(void* const* d_in, const int* in_sizes, int n_in,
                              void* d_out, int out_size, void* d_ws, size_t ws_size,
                              hipStream_t stream) {
    const float* feat  = (const float*)d_in[0];   // [2048] f32
    const int*   label = (const int*)d_in[1];     // [1] int32
    const float* proto = (const float*)d_in[2];   // [10000,4,2048] f32
    float* out = (float*)d_out;                   // [1] f32

    float* wave_min = (float*)d_ws;               // [8000]
    float* wave_sum = wave_min + NWAVES;          // [8000]
    float* d_label  = wave_sum + NWAVES;          // [4]

    dist_kernel<<<NBLOCKS, 256, 0, stream>>>(
        (const float4*)proto, (const float4*)feat, label,
        wave_min, wave_sum, d_label);
    finalize_kernel<<<1, 256, 0, stream>>>(wave_min, wave_sum, d_label, out);
}

// Round 3
// 435.868 us; speedup vs baseline: 1.0924x; 1.0553x over previous
//
#include <hip/hip_runtime.h>

// Problem constants (match reference)
#define C_CLASSES 10000
#define K_PROTO   4
#define D_DIM     2048
#define ROWS      (C_CLASSES * K_PROTO)   // 40000
#define D_VEC     (D_DIM / 4)             // 512 float4 per row
#define RPW       4                       // rows per wave (aligns with K_PROTO!)
#define NBLOCKS   2500                    // 4 waves/block * 4 rows = 16 rows/block
#define NWAVES    (NBLOCKS * 4)           // 10000 waves

// Kernel 1: each wave owns 4 consecutive rows == exactly one class block.
// Feature (8 KB) in registers; proto loads double-buffered 2 rows deep
// (16 KB in flight/wave). Transposed 4-accumulator butterfly: 16 shuffles
// leaves lanes 0..3 holding d[row0..row0+3]; wave-local (min, sum-exp) pair
// stored as float2; label wave scatters its 4 distances directly.
__global__ __launch_bounds__(256) void dist_kernel(const float4* __restrict__ proto,
                                                   const float4* __restrict__ feat,
                                                   const int* __restrict__ label,
                                                   float2* __restrict__ wave_pair,
                                                   float* __restrict__ d_label) {
    const int wave = (blockIdx.x << 2) | (threadIdx.x >> 6);
    const int lane = threadIdx.x & 63;
    const int lbl  = label[0];
    const float4* p0 = proto + (size_t)wave * RPW * D_VEC;

    float4 f[8];
#pragma unroll
    for (int j = 0; j < 8; ++j) f[j] = feat[j * 64 + lane];

    float4 a[8], b[8];
#pragma unroll
    for (int j = 0; j < 8; ++j) a[j] = p0[j * 64 + lane];               // row 0
#pragma unroll
    for (int j = 0; j < 8; ++j) b[j] = p0[D_VEC + j * 64 + lane];       // row 1

    float acc0 = 0.f, acc1 = 0.f, acc2 = 0.f, acc3 = 0.f;
#pragma unroll
    for (int j = 0; j < 8; ++j) {                                       // compute row 0
        const float dx = a[j].x - f[j].x, dy = a[j].y - f[j].y;
        const float dz = a[j].z - f[j].z, dw = a[j].w - f[j].w;
        acc0 += dx * dx + dy * dy + dz * dz + dw * dw;
    }
#pragma unroll
    for (int j = 0; j < 8; ++j) a[j] = p0[2 * D_VEC + j * 64 + lane];   // row 2
#pragma unroll
    for (int j = 0; j < 8; ++j) {                                       // compute row 1
        const float dx = b[j].x - f[j].x, dy = b[j].y - f[j].y;
        const float dz = b[j].z - f[j].z, dw = b[j].w - f[j].w;
        acc1 += dx * dx + dy * dy + dz * dz + dw * dw;
    }
#pragma unroll
    for (int j = 0; j < 8; ++j) b[j] = p0[3 * D_VEC + j * 64 + lane];   // row 3
#pragma unroll
    for (int j = 0; j < 8; ++j) {                                       // compute row 2
        const float dx = a[j].x - f[j].x, dy = a[j].y - f[j].y;
        const float dz = a[j].z - f[j].z, dw = a[j].w - f[j].w;
        acc2 += dx * dx + dy * dy + dz * dz + dw * dw;
    }
#pragma unroll
    for (int j = 0; j < 8; ++j) {                                       // compute row 3
        const float dx = b[j].x - f[j].x, dy = b[j].y - f[j].y;
        const float dz = b[j].z - f[j].z, dw = b[j].w - f[j].w;
        acc3 += dx * dx + dy * dy + dz * dz + dw * dw;
    }

    // Transposed reduce. Stage 1: sum each acc within 4-lane groups (bits 0-1).
#pragma unroll
    for (int m = 1; m <= 2; m <<= 1) {
        acc0 += __shfl_xor(acc0, m, 64);
        acc1 += __shfl_xor(acc1, m, 64);
        acc2 += __shfl_xor(acc2, m, 64);
        acc3 += __shfl_xor(acc3, m, 64);
    }
    // Select this lane's row by lane&3.
    const int l3 = lane & 3;
    float v = acc0;
    v = (l3 == 1) ? acc1 : v;
    v = (l3 == 2) ? acc2 : v;
    v = (l3 == 3) ? acc3 : v;
    // Stage 2: sum across the 16 groups (bits 2-5). Lane L ends with d[row0+(L&3)].
#pragma unroll
    for (int m = 4; m <= 32; m <<= 1) v += __shfl_xor(v, m, 64);

    // Wave-local logsumexp pair over the 4 rows (within each 4-lane subgroup).
    float mn = fminf(v, __shfl_xor(v, 1, 64));
    mn = fminf(mn, __shfl_xor(mn, 2, 64));
    float s = expf(mn - v);
    s += __shfl_xor(s, 1, 64);
    s += __shfl_xor(s, 2, 64);

    if (lane == 0) wave_pair[wave] = make_float2(mn, s);
    if (wave == lbl && lane < 4) d_label[lane] = v;   // wave lbl == class lbl
}

// Kernel 2: single block combines 10000 wave pairs (80 KB, L2-hot).
__global__ __launch_bounds__(256) void finalize_kernel(const float2* __restrict__ wave_pair,
                                                       const float* __restrict__ d_label,
                                                       float* __restrict__ out) {
    __shared__ float red[256];
    const int tid = threadIdx.x;

    float m = 3.402823466e38f;
    for (int i = tid; i < NWAVES; i += 256) m = fminf(m, wave_pair[i].x);
    red[tid] = m;
    __syncthreads();
    for (int s = 128; s > 0; s >>= 1) {
        if (tid < s) red[tid] = fminf(red[tid], red[tid + s]);
        __syncthreads();
    }
    const float dmin = red[0];
    __syncthreads();

    float acc = 0.0f;
    for (int i = tid; i < NWAVES; i += 256) {
        const float2 p = wave_pair[i];
        acc += p.y * expf(dmin - p.x);
    }
    red[tid] = acc;
    __syncthreads();
    for (int s = 128; s > 0; s >>= 1) {
        if (tid < s) red[tid] += red[tid + s];
        __syncthreads();
    }

    if (tid == 0) {
        const float log_one = -dmin + logf(red[0]);
        float p = 0.0f;
#pragma unroll
        for (int k = 0; k < K_PROTO; ++k) p += log_one + d_label[k];
        out[0] = p;
    }
}

extern "C" void kernel_launch(void* const* d_in, const int* in_sizes, int n_in,
                              void* d_out, int out_size, void* d_ws, size_t ws_size,
                              hipStream_t stream) {
    const float* feat  = (const float*)d_in[0];   // [2048] f32
    const int*   label = (const int*)d_in[1];     // [1] int32
    const float* proto = (const float*)d_in[2];   // [10000,4,2048] f32
    float* out = (float*)d_out;                   // [1] f32

    float2* wave_pair = (float2*)d_ws;            // [10000] (min, sumexp)
    float*  d_label   = (float*)(wave_pair + NWAVES);  // [4]

    dist_kernel<<<NBLOCKS, 256, 0, stream>>>(
        (const float4*)proto, (const float4*)feat, label, wave_pair, d_label);
    finalize_kernel<<<1, 256, 0, stream>>>(wave_pair, d_label, out);
}

// Round 4
// 408.291 us; speedup vs baseline: 1.1662x; 1.0675x over previous
//
#include <hip/hip_runtime.h>

// Problem constants (match reference)
#define C_CLASSES 10000
#define K_PROTO   4
#define D_DIM     2048
#define ROWS      (C_CLASSES * K_PROTO)   // 40000
#define D_VEC     (D_DIM / 4)             // 512 float4 per row
#define RPW       4                       // rows per wave (== K_PROTO)
#define NBLOCKS   2500                    // 4 waves/block * 4 rows = 16 rows/block
#define NWAVES    (NBLOCKS * 4)           // 10000 waves

typedef float v4f __attribute__((ext_vector_type(4)));

// Kernel 1: each wave owns one class block (4 rows, 32 KB contiguous).
// Depth-4: all 32 proto loads (nontemporal, streamed once) issued before any
// compute -> 32 KB in flight per wave. Feature (8 KB) stays in 32 VGPRs.
// Transposed butterfly leaves lanes 0..3 of each 4-lane group holding
// d[row0..row0+3]; wave writes one (min, sumexp) float2 pair.
__global__ __launch_bounds__(256) void dist_kernel(const v4f* __restrict__ proto,
                                                   const v4f* __restrict__ feat,
                                                   const int* __restrict__ label,
                                                   float2* __restrict__ wave_pair,
                                                   float* __restrict__ d_label) {
    const int wave = (blockIdx.x << 2) | (threadIdx.x >> 6);
    const int lane = threadIdx.x & 63;
    const int lbl  = label[0];
    const v4f* p0  = proto + (size_t)wave * RPW * D_VEC;

    // Feature into registers once (cached loads — reused by every wave).
    v4f f[8];
#pragma unroll
    for (int j = 0; j < 8; ++j) f[j] = feat[j * 64 + lane];

    // Issue ALL proto loads up front (nt: evict-first streaming).
    v4f r[RPW][8];
#pragma unroll
    for (int rr = 0; rr < RPW; ++rr)
#pragma unroll
        for (int j = 0; j < 8; ++j)
            r[rr][j] = __builtin_nontemporal_load(&p0[rr * D_VEC + j * 64 + lane]);

    float acc[RPW];
#pragma unroll
    for (int rr = 0; rr < RPW; ++rr) {
        float a = 0.0f;
#pragma unroll
        for (int j = 0; j < 8; ++j) {
            const float dx = r[rr][j].x - f[j].x;
            const float dy = r[rr][j].y - f[j].y;
            const float dz = r[rr][j].z - f[j].z;
            const float dw = r[rr][j].w - f[j].w;
            a += dx * dx + dy * dy + dz * dz + dw * dw;
        }
        acc[rr] = a;
    }

    // Transposed reduce. Stage 1: sum each acc within 4-lane groups (bits 0-1).
#pragma unroll
    for (int m = 1; m <= 2; m <<= 1) {
        acc[0] += __shfl_xor(acc[0], m, 64);
        acc[1] += __shfl_xor(acc[1], m, 64);
        acc[2] += __shfl_xor(acc[2], m, 64);
        acc[3] += __shfl_xor(acc[3], m, 64);
    }
    const int l3 = lane & 3;
    float v = acc[0];
    v = (l3 == 1) ? acc[1] : v;
    v = (l3 == 2) ? acc[2] : v;
    v = (l3 == 3) ? acc[3] : v;
    // Stage 2: sum across the 16 groups (bits 2-5). Lane L holds d[row0+(L&3)].
#pragma unroll
    for (int m = 4; m <= 32; m <<= 1) v += __shfl_xor(v, m, 64);

    // Wave-local logsumexp pair over the 4 rows.
    float mn = fminf(v, __shfl_xor(v, 1, 64));
    mn = fminf(mn, __shfl_xor(mn, 2, 64));
    float s = expf(mn - v);
    s += __shfl_xor(s, 1, 64);
    s += __shfl_xor(s, 2, 64);

    if (lane == 0) wave_pair[wave] = make_float2(mn, s);
    if (wave == lbl && lane < 4) d_label[lane] = v;
}

// Kernel 2: one 1024-thread block combines 10000 wave pairs (80 KB, L2-hot).
// float4 loads grab two (min,sum) pairs at once.
__global__ __launch_bounds__(1024) void finalize_kernel(const float4* __restrict__ pairs4,
                                                        const float* __restrict__ d_label,
                                                        float* __restrict__ out) {
    __shared__ float sm[20];
    const int tid  = threadIdx.x;
    const int lane = tid & 63;
    const int wid  = tid >> 6;          // 0..15
    const int N4   = NWAVES / 2;        // 5000 float4

    // Pass 1: global min of d.
    float m = 3.402823466e38f;
    for (int i = tid; i < N4; i += 1024) {
        const float4 p = pairs4[i];
        m = fminf(m, fminf(p.x, p.z));
    }
#pragma unroll
    for (int off = 1; off < 64; off <<= 1) m = fminf(m, __shfl_xor(m, off, 64));
    if (lane == 0) sm[wid] = m;
    __syncthreads();
    if (tid == 0) {
        float mm = sm[0];
#pragma unroll
        for (int i = 1; i < 16; ++i) mm = fminf(mm, sm[i]);
        sm[16] = mm;
    }
    __syncthreads();
    const float dmin = sm[16];

    // Pass 2: sum of S_w * exp(dmin - min_w).
    float acc = 0.0f;
    for (int i = tid; i < N4; i += 1024) {
        const float4 p = pairs4[i];
        acc += p.y * expf(dmin - p.x) + p.w * expf(dmin - p.z);
    }
#pragma unroll
    for (int off = 1; off < 64; off <<= 1) acc += __shfl_xor(acc, off, 64);
    if (lane == 0) sm[wid] = acc;
    __syncthreads();
    if (tid == 0) {
        float ss = 0.0f;
#pragma unroll
        for (int i = 0; i < 16; ++i) ss += sm[i];
        const float log_one = -dmin + logf(ss);
        float p = 0.0f;
#pragma unroll
        for (int k = 0; k < K_PROTO; ++k) p += log_one + d_label[k];
        out[0] = p;
    }
}

extern "C" void kernel_launch(void* const* d_in, const int* in_sizes, int n_in,
                              void* d_out, int out_size, void* d_ws, size_t ws_size,
                              hipStream_t stream) {
    const float* feat  = (const float*)d_in[0];   // [2048] f32
    const int*   label = (const int*)d_in[1];     // [1] int32
    const float* proto = (const float*)d_in[2];   // [10000,4,2048] f32
    float* out = (float*)d_out;                   // [1] f32

    float2* wave_pair = (float2*)d_ws;            // [10000] (min, sumexp)
    float*  d_label   = (float*)(wave_pair + NWAVES);  // [4]

    dist_kernel<<<NBLOCKS, 256, 0, stream>>>(
        (const v4f*)proto, (const v4f*)feat, label, wave_pair, d_label);
    finalize_kernel<<<1, 1024, 0, stream>>>((const float4*)wave_pair, d_label, out);
}